// Round 10
// baseline (102.291 us; speedup 1.0000x reference)
//
#include <hip/hip_runtime.h>

#define F_IN  128
#define HID   16
#define CF_IN 64
#define NTHR  256
#define TN    256          // nodes per block (64 per wave)
#define CK4   4            // float4s per node per chunk
#define NCH   8            // chunks: 32 k4 / CK4

// GCN aggregation is exactly the identity here (row==col after the reference's
// broadcast+reshape), so each conv is x@W + b. edge_index is never read.
//
// Node path: wave-autonomous 64-node tiles. x staged global->LDS via
// global_load_lds (width 16), double-buffered with counted s_waitcnt vmcnt(4)
// -- no __syncthreads in the hot loop, no ds_write, no lgkm pollution of the
// uniform weight loads. LDS is XOR-swizzled (p = q ^ (n&3)); since
// global_load_lds writes linearly, the swizzle is applied on the per-lane
// GLOBAL source address and on the read (both-sides rule). Each stage instr
// reads 16 fully-used 64B segments (fill-like), fixing R8's 16B/line waste.

__device__ __forceinline__ void gload16(const void* g, void* l) {
    __builtin_amdgcn_global_load_lds(
        (const __attribute__((address_space(1))) void*)g,
        (__attribute__((address_space(3))) void*)l, 16, 0, 0);
}

__global__ __launch_bounds__(NTHR) void fused_kernel(
    const float* __restrict__ x, const float* __restrict__ xc,
    const float* __restrict__ W1, const float* __restrict__ b1,
    const float* __restrict__ W2, const float* __restrict__ b2,
    const float* __restrict__ Wn, const float* __restrict__ bn,
    const float* __restrict__ Wc1, const float* __restrict__ bc1,
    const float* __restrict__ Wc2, const float* __restrict__ bc2,
    float* __restrict__ pN, float* __restrict__ pC,
    int N, int B, int C, int totalN, int nodeBlocks, int colBlocks)
{
    __shared__ __align__(16) float4 xbuf[2][TN * CK4];   // 2 x 16 KB
    __shared__ float sred[4 * 8];
    const int t = threadIdx.x;
    const int bx = blockIdx.x;
    const int wave = t >> 6, lane = t & 63;

    if (bx < nodeBlocks) {
        // ---------------- node path ----------------
        const long tileBase = (long)bx * TN;
        const long maxf4 = (long)totalN * 32 - 1;
        const float4* __restrict__ gx4 = (const float4*)x;

        // stage chunk c of this wave's 64 nodes into xbuf[buf]:
        // call i: lane stages node ng = wave*64 + i*16 + (lane>>2), p = lane&3
        // LDS slot ng*4+p holds global k4local (p ^ (ng&3))  [involution]
#define STAGE(c, buf)                                                         \
        {                                                                     \
            _Pragma("unroll")                                                 \
            for (int i = 0; i < 4; ++i) {                                     \
                const int ng = wave * 64 + i * 16 + (lane >> 2);              \
                const int p  = lane & 3;                                      \
                long f4i = (tileBase + ng) * 32 + (c) * 4 + (p ^ (ng & 3));   \
                if (f4i > maxf4) f4i = maxf4;                                 \
                gload16(gx4 + f4i, &xbuf[buf][wave * 256 + i * 64]);          \
            }                                                                 \
        }

        float acc[HID];
        {
            const float4* __restrict__ bb = (const float4*)b1;   // uniform
            const float4 c0 = bb[0], c1 = bb[1], c2 = bb[2], c3 = bb[3];
            acc[0]=c0.x;  acc[1]=c0.y;  acc[2]=c0.z;  acc[3]=c0.w;
            acc[4]=c1.x;  acc[5]=c1.y;  acc[6]=c1.z;  acc[7]=c1.w;
            acc[8]=c2.x;  acc[9]=c2.y;  acc[10]=c2.z; acc[11]=c2.w;
            acc[12]=c3.x; acc[13]=c3.y; acc[14]=c3.z; acc[15]=c3.w;
        }

        STAGE(0, 0)
        int cur = 0;
#pragma unroll
        for (int c = 0; c < NCH; ++c) {
            if (c + 1 < NCH) {
                STAGE(c + 1, cur ^ 1)
                asm volatile("s_waitcnt vmcnt(4)" ::: "memory");
            } else {
                asm volatile("s_waitcnt vmcnt(0)" ::: "memory");
            }
            __builtin_amdgcn_sched_barrier(0);

            const int n = t;   // thread-per-node; n*4 lies in this wave's region
#pragma unroll
            for (int q = 0; q < CK4; ++q) {
                const float4 xv = xbuf[cur][n * 4 + (q ^ (n & 3))];
                const float4* __restrict__ wb =
                    (const float4*)(W1 + (c * CK4 + q) * 4 * HID);  // uniform
#pragma unroll
                for (int r = 0; r < 4; ++r) {
                    const float xs = (r == 0) ? xv.x : (r == 1) ? xv.y
                                   : (r == 2) ? xv.z : xv.w;
                    const float4 w0  = wb[r * 4 + 0];
                    const float4 w1v = wb[r * 4 + 1];
                    const float4 w2v = wb[r * 4 + 2];
                    const float4 w3v = wb[r * 4 + 3];
                    acc[0]  = fmaf(xs, w0.x,  acc[0]);
                    acc[1]  = fmaf(xs, w0.y,  acc[1]);
                    acc[2]  = fmaf(xs, w0.z,  acc[2]);
                    acc[3]  = fmaf(xs, w0.w,  acc[3]);
                    acc[4]  = fmaf(xs, w1v.x, acc[4]);
                    acc[5]  = fmaf(xs, w1v.y, acc[5]);
                    acc[6]  = fmaf(xs, w1v.z, acc[6]);
                    acc[7]  = fmaf(xs, w1v.w, acc[7]);
                    acc[8]  = fmaf(xs, w2v.x, acc[8]);
                    acc[9]  = fmaf(xs, w2v.y, acc[9]);
                    acc[10] = fmaf(xs, w2v.z, acc[10]);
                    acc[11] = fmaf(xs, w2v.w, acc[11]);
                    acc[12] = fmaf(xs, w3v.x, acc[12]);
                    acc[13] = fmaf(xs, w3v.y, acc[13]);
                    acc[14] = fmaf(xs, w3v.z, acc[14]);
                    acc[15] = fmaf(xs, w3v.w, acc[15]);
                }
            }
            cur ^= 1;
        }
#undef STAGE

        // layer 2 (16x16) + relu, layer 3 (16->1): uniform weights, registers
        float h1[HID];
#pragma unroll
        for (int j = 0; j < HID; ++j) h1[j] = fmaxf(acc[j], 0.f);
        float h2[HID];
        {
            const float4* __restrict__ bb = (const float4*)b2;   // uniform
            const float4 c0 = bb[0], c1 = bb[1], c2 = bb[2], c3 = bb[3];
            h2[0]=c0.x;  h2[1]=c0.y;  h2[2]=c0.z;  h2[3]=c0.w;
            h2[4]=c1.x;  h2[5]=c1.y;  h2[6]=c1.z;  h2[7]=c1.w;
            h2[8]=c2.x;  h2[9]=c2.y;  h2[10]=c2.z; h2[11]=c2.w;
            h2[12]=c3.x; h2[13]=c3.y; h2[14]=c3.z; h2[15]=c3.w;
        }
#pragma unroll
        for (int kk = 0; kk < HID; ++kk) {
            const float hk = h1[kk];
            const float4* __restrict__ wr = (const float4*)(W2 + kk * HID);
            const float4 w0 = wr[0], w1v = wr[1], w2v = wr[2], w3v = wr[3];
            h2[0]  = fmaf(hk, w0.x,  h2[0]);
            h2[1]  = fmaf(hk, w0.y,  h2[1]);
            h2[2]  = fmaf(hk, w0.z,  h2[2]);
            h2[3]  = fmaf(hk, w0.w,  h2[3]);
            h2[4]  = fmaf(hk, w1v.x, h2[4]);
            h2[5]  = fmaf(hk, w1v.y, h2[5]);
            h2[6]  = fmaf(hk, w1v.z, h2[6]);
            h2[7]  = fmaf(hk, w1v.w, h2[7]);
            h2[8]  = fmaf(hk, w2v.x, h2[8]);
            h2[9]  = fmaf(hk, w2v.y, h2[9]);
            h2[10] = fmaf(hk, w2v.z, h2[10]);
            h2[11] = fmaf(hk, w2v.w, h2[11]);
            h2[12] = fmaf(hk, w3v.x, h2[12]);
            h2[13] = fmaf(hk, w3v.y, h2[13]);
            h2[14] = fmaf(hk, w3v.z, h2[14]);
            h2[15] = fmaf(hk, w3v.w, h2[15]);
        }
        float o = bn[0];
#pragma unroll
        for (int kk = 0; kk < HID; ++kk)
            o = fmaf(fmaxf(h2[kk], 0.f), Wn[kk], o);

        const long node = tileBase + t;
        const bool valid = (node < totalN);
        const int myb = valid ? (int)(node / N) : 0;
        const float val = valid ? o : 0.f;

        // per-batch masked block reduction (deterministic)
        for (int b = 0; b < B; ++b) {
            float s = (myb == b) ? val : 0.f;
#pragma unroll
            for (int off = 32; off; off >>= 1) s += __shfl_down(s, off, 64);
            if (lane == 0) sred[wave * B + b] = s;
        }
        __syncthreads();
        if (t == 0) {
            for (int b = 0; b < B; ++b)
                pN[(long)b * nodeBlocks + bx] =
                    (sred[0 * B + b] + sred[1 * B + b]) +
                    (sred[2 * B + b] + sred[3 * B + b]);
        }
    } else {
        // ---------------- col path (tiny, R8 structure) ----------------
        const int cb = bx - nodeBlocks;
        const int totC = B * C;
        const int c = cb * NTHR + t;
        const bool valid = (c < totC);
        const int cc = valid ? c : totC - 1;
        const float4* __restrict__ row = (const float4*)(xc + (long)cc * CF_IN);

        float acc[HID];
        {
            const float4* __restrict__ bb = (const float4*)bc1;  // uniform
            const float4 c0 = bb[0], c1 = bb[1], c2 = bb[2], c3 = bb[3];
            acc[0]=c0.x;  acc[1]=c0.y;  acc[2]=c0.z;  acc[3]=c0.w;
            acc[4]=c1.x;  acc[5]=c1.y;  acc[6]=c1.z;  acc[7]=c1.w;
            acc[8]=c2.x;  acc[9]=c2.y;  acc[10]=c2.z; acc[11]=c2.w;
            acc[12]=c3.x; acc[13]=c3.y; acc[14]=c3.z; acc[15]=c3.w;
        }
#pragma unroll 4
        for (int k4 = 0; k4 < CF_IN / 4; ++k4) {
            const float4 xv = row[k4];
            const float4* __restrict__ wb =
                (const float4*)(Wc1 + k4 * 4 * HID);
#pragma unroll
            for (int r = 0; r < 4; ++r) {
                const float xs = (r == 0) ? xv.x : (r == 1) ? xv.y
                               : (r == 2) ? xv.z : xv.w;
                const float4 w0  = wb[r * 4 + 0];
                const float4 w1v = wb[r * 4 + 1];
                const float4 w2v = wb[r * 4 + 2];
                const float4 w3v = wb[r * 4 + 3];
                acc[0]  = fmaf(xs, w0.x,  acc[0]);
                acc[1]  = fmaf(xs, w0.y,  acc[1]);
                acc[2]  = fmaf(xs, w0.z,  acc[2]);
                acc[3]  = fmaf(xs, w0.w,  acc[3]);
                acc[4]  = fmaf(xs, w1v.x, acc[4]);
                acc[5]  = fmaf(xs, w1v.y, acc[5]);
                acc[6]  = fmaf(xs, w1v.z, acc[6]);
                acc[7]  = fmaf(xs, w1v.w, acc[7]);
                acc[8]  = fmaf(xs, w2v.x, acc[8]);
                acc[9]  = fmaf(xs, w2v.y, acc[9]);
                acc[10] = fmaf(xs, w2v.z, acc[10]);
                acc[11] = fmaf(xs, w2v.w, acc[11]);
                acc[12] = fmaf(xs, w3v.x, acc[12]);
                acc[13] = fmaf(xs, w3v.y, acc[13]);
                acc[14] = fmaf(xs, w3v.z, acc[14]);
                acc[15] = fmaf(xs, w3v.w, acc[15]);
            }
        }
        float o = bc2[0];
#pragma unroll
        for (int j = 0; j < HID; ++j)
            o = fmaf(fmaxf(acc[j], 0.f), Wc2[j], o);

        const int myb = cc / C;
        const float val = valid ? o : 0.f;
        for (int b = 0; b < B; ++b) {
            float s = (myb == b) ? val : 0.f;
#pragma unroll
            for (int off = 32; off; off >>= 1) s += __shfl_down(s, off, 64);
            if (lane == 0) sred[wave * B + b] = s;
        }
        __syncthreads();
        if (t == 0) {
            for (int b = 0; b < B; ++b)
                pC[(long)b * colBlocks + cb] =
                    (sred[0 * B + b] + sred[1 * B + b]) +
                    (sred[2 * B + b] + sred[3 * B + b]);
        }
    }
}

__global__ __launch_bounds__(256) void finish_kernel(
    const float* __restrict__ pN, const float* __restrict__ pC,
    const float* __restrict__ Wf, const float* __restrict__ bf,
    const float* __restrict__ Wo, const float* __restrict__ bo,
    float* __restrict__ out, int nWN, int nWC, int N, int C, int B)
{
    const int t = threadIdx.x;
    const int wave = t >> 6, lane = t & 63;
    __shared__ float s[16];

    for (int p = wave; p < 2 * B; p += 4) {
        const int b = p >> 1, kind = p & 1;
        float v = 0.f;
        if (kind == 0) {
            for (int i = lane; i < nWN; i += 64) v += pN[(long)b * nWN + i];
        } else {
            for (int i = lane; i < nWC; i += 64) v += pC[(long)b * nWC + i];
        }
#pragma unroll
        for (int off = 32; off; off >>= 1) v += __shfl_down(v, off, 64);
        if (lane == 0) s[p] = v;
    }
    __syncthreads();

    if (t == 0) {
        for (int b = 0; b < B; ++b) {
            const float navg = s[2 * b + 0] / (float)N;
            const float cavg = s[2 * b + 1] / (float)C;
            float o = bo[0];
#pragma unroll
            for (int j = 0; j < HID; ++j) {
                const float h = fmaf(navg, Wf[j], fmaf(cavg, Wf[HID + j], bf[j]));
                o = fmaf(fmaxf(h, 0.f), Wo[j], o);
            }
            out[b] = o;
        }
    }
}

extern "C" void kernel_launch(void* const* d_in, const int* in_sizes, int n_in,
                              void* d_out, int out_size, void* d_ws, size_t ws_size,
                              hipStream_t stream) {
    const float* x   = (const float*)d_in[0];
    const float* xc  = (const float*)d_in[1];
    // d_in[2] = edge_index: unused (row==col degeneracy -> GCN aggregation is identity)
    const float* W1  = (const float*)d_in[3];
    const float* b1  = (const float*)d_in[4];
    const float* W2  = (const float*)d_in[5];
    const float* b2  = (const float*)d_in[6];
    const float* Wn  = (const float*)d_in[7];
    const float* bn  = (const float*)d_in[8];
    const float* Wc1 = (const float*)d_in[9];
    const float* bc1 = (const float*)d_in[10];
    const float* Wc2 = (const float*)d_in[11];
    const float* bc2 = (const float*)d_in[12];
    const float* Wf  = (const float*)d_in[13];
    const float* bf  = (const float*)d_in[14];
    const float* Wo  = (const float*)d_in[15];
    const float* bo  = (const float*)d_in[16];

    const int C = 1000;
    const int B = in_sizes[1] / (C * CF_IN);     // col_features [B, 1000, 64]
    const int N = in_sizes[0] / (B * F_IN);      // node_features [B, N, 128]
    const int totalN = B * N;                    // 200000

    const int nodeBlocks = (totalN + TN - 1) / TN;       // 782
    const int colBlocks  = (B * C + NTHR - 1) / NTHR;    // 8

    float* pN = (float*)d_ws;                    // [B][nodeBlocks], always overwritten
    float* pC = pN + (long)B * nodeBlocks;       // [B][colBlocks]

    fused_kernel<<<nodeBlocks + colBlocks, NTHR, 0, stream>>>(
        x, xc, W1, b1, W2, b2, Wn, bn, Wc1, bc1, Wc2, bc2,
        pN, pC, N, B, C, totalN, nodeBlocks, colBlocks);
    finish_kernel<<<1, 256, 0, stream>>>(pN, pC, Wf, bf, Wo, bo, (float*)d_out,
                                         nodeBlocks, colBlocks, N, C, B);
}

// Round 11
// 45.339 us; speedup vs baseline: 2.2561x; 2.2561x over previous
//
#include <hip/hip_runtime.h>

#define F_IN  128
#define HID   16
#define CF_IN 64
#define NTHR  256
#define H1STR 20   // h1 transpose row stride (floats): 16B-aligned, ~2-way banks

// quad_perm broadcast of lane S within each 4-lane group: pure-VALU DPP mov
// (NOT __shfl: that may lower to ds_bpermute/ds_swizzle on the DS pipe).
#define QB(v, S) __int_as_float(__builtin_amdgcn_mov_dpp(                 \
        __float_as_int(v), (S) * 0x55, 0xf, 0xf, 0))

// 16 FMAs for node S of this lane's quad: broadcast x(4 k) x this lane's 4 j
#define QSTEP(S)                                                          \
    {                                                                     \
        const float bx0 = QB(xv.x, S);                                    \
        const float bx1 = QB(xv.y, S);                                    \
        const float bx2 = QB(xv.z, S);                                    \
        const float bx3 = QB(xv.w, S);                                    \
        acc[S][0] = fmaf(bx0, wq0.x, acc[S][0]);                          \
        acc[S][1] = fmaf(bx0, wq0.y, acc[S][1]);                          \
        acc[S][2] = fmaf(bx0, wq0.z, acc[S][2]);                          \
        acc[S][3] = fmaf(bx0, wq0.w, acc[S][3]);                          \
        acc[S][0] = fmaf(bx1, wq1.x, acc[S][0]);                          \
        acc[S][1] = fmaf(bx1, wq1.y, acc[S][1]);                          \
        acc[S][2] = fmaf(bx1, wq1.z, acc[S][2]);                          \
        acc[S][3] = fmaf(bx1, wq1.w, acc[S][3]);                          \
        acc[S][0] = fmaf(bx2, wq2.x, acc[S][0]);                          \
        acc[S][1] = fmaf(bx2, wq2.y, acc[S][1]);                          \
        acc[S][2] = fmaf(bx2, wq2.z, acc[S][2]);                          \
        acc[S][3] = fmaf(bx2, wq2.w, acc[S][3]);                          \
        acc[S][0] = fmaf(bx3, wq3.x, acc[S][0]);                          \
        acc[S][1] = fmaf(bx3, wq3.y, acc[S][1]);                          \
        acc[S][2] = fmaf(bx3, wq3.z, acc[S][2]);                          \
        acc[S][3] = fmaf(bx3, wq3.w, acc[S][3]);                          \
    }

// GCN aggregation is exactly the identity here (row==col after the reference's
// broadcast+reshape), so each conv is x@W + b. edge_index is never read.
//
// Node path layer 1: 4-lane quads. Lane (g,u): x row of node 4g+u (R8's exact
// per-lane float4 stream, L1-reuses lines 4x), weights only for j-quad u
// (4 float4/k4 vs 16 -> 4x fewer weight-delivery instructions, the measured
// ~21us wall shared by R1/R5/R8). DPP broadcasts x across the quad. Then a
// once-per-wave LDS transpose gives each lane its node's full h1; layers 2/3
// and the reduction are R8-verbatim.

__global__ __launch_bounds__(NTHR) void fused_kernel(
    const float* __restrict__ x, const float* __restrict__ xc,
    const float* __restrict__ W1, const float* __restrict__ b1,
    const float* __restrict__ W2, const float* __restrict__ b2,
    const float* __restrict__ Wn, const float* __restrict__ bn,
    const float* __restrict__ Wc1, const float* __restrict__ bc1,
    const float* __restrict__ Wc2, const float* __restrict__ bc2,
    float* __restrict__ pN, float* __restrict__ pC,
    int N, int B, int C, int totalN, int nodeBlocks, int colBlocks)
{
    __shared__ __align__(16) float h1T[NTHR * H1STR];   // 20 KB
    __shared__ float sred[4 * 8];
    const int t = threadIdx.x;
    const int bx = blockIdx.x;
    const int wave = t >> 6;

    if (bx < nodeBlocks) {
        // ---------------- node path ----------------
        const int n = bx * NTHR + t;
        const bool valid = (n < totalN);
        const int nc = valid ? n : totalN - 1;
        const float4* __restrict__ row = (const float4*)(x + (long)nc * F_IN);
        const int u = t & 3;
        const float4* __restrict__ wrow = (const float4*)(W1 + 4 * u);

        float acc[4][4];
        {
            const float4 bv = *(const float4*)(b1 + 4 * u);
#pragma unroll
            for (int s = 0; s < 4; ++s) {
                acc[s][0] = bv.x; acc[s][1] = bv.y;
                acc[s][2] = bv.z; acc[s][3] = bv.w;
            }
        }

#pragma unroll 4
        for (int k4 = 0; k4 < F_IN / 4; ++k4) {
            const float4 xv = row[k4];
            const float4 wq0 = wrow[(k4 * 4 + 0) * 4];
            const float4 wq1 = wrow[(k4 * 4 + 1) * 4];
            const float4 wq2 = wrow[(k4 * 4 + 2) * 4];
            const float4 wq3 = wrow[(k4 * 4 + 3) * 4];
            QSTEP(0) QSTEP(1) QSTEP(2) QSTEP(3)
        }

        // relu + in-wave transpose (quad j-slices -> full h1 per lane)
        const int qb = t & ~3;
#pragma unroll
        for (int s = 0; s < 4; ++s) {
            float4 hv;
            hv.x = fmaxf(acc[s][0], 0.f);
            hv.y = fmaxf(acc[s][1], 0.f);
            hv.z = fmaxf(acc[s][2], 0.f);
            hv.w = fmaxf(acc[s][3], 0.f);
            *(float4*)&h1T[(qb + s) * H1STR + 4 * u] = hv;
        }
        float h1[HID];
#pragma unroll
        for (int q = 0; q < 4; ++q) {
            const float4 hv = *(const float4*)&h1T[t * H1STR + 4 * q];
            h1[4 * q + 0] = hv.x; h1[4 * q + 1] = hv.y;
            h1[4 * q + 2] = hv.z; h1[4 * q + 3] = hv.w;
        }

        // layer 2 (16x16) + relu, layer 3 (16->1): uniform weights, registers
        float h2[HID];
        {
            const float4* __restrict__ bb = (const float4*)b2;   // uniform
            const float4 c0 = bb[0], c1 = bb[1], c2 = bb[2], c3 = bb[3];
            h2[0]=c0.x;  h2[1]=c0.y;  h2[2]=c0.z;  h2[3]=c0.w;
            h2[4]=c1.x;  h2[5]=c1.y;  h2[6]=c1.z;  h2[7]=c1.w;
            h2[8]=c2.x;  h2[9]=c2.y;  h2[10]=c2.z; h2[11]=c2.w;
            h2[12]=c3.x; h2[13]=c3.y; h2[14]=c3.z; h2[15]=c3.w;
        }
#pragma unroll
        for (int kk = 0; kk < HID; ++kk) {
            const float hk = h1[kk];
            const float4* __restrict__ wr = (const float4*)(W2 + kk * HID);
            const float4 w0 = wr[0], w1v = wr[1], w2v = wr[2], w3v = wr[3];
            h2[0]  = fmaf(hk, w0.x,  h2[0]);
            h2[1]  = fmaf(hk, w0.y,  h2[1]);
            h2[2]  = fmaf(hk, w0.z,  h2[2]);
            h2[3]  = fmaf(hk, w0.w,  h2[3]);
            h2[4]  = fmaf(hk, w1v.x, h2[4]);
            h2[5]  = fmaf(hk, w1v.y, h2[5]);
            h2[6]  = fmaf(hk, w1v.z, h2[6]);
            h2[7]  = fmaf(hk, w1v.w, h2[7]);
            h2[8]  = fmaf(hk, w2v.x, h2[8]);
            h2[9]  = fmaf(hk, w2v.y, h2[9]);
            h2[10] = fmaf(hk, w2v.z, h2[10]);
            h2[11] = fmaf(hk, w2v.w, h2[11]);
            h2[12] = fmaf(hk, w3v.x, h2[12]);
            h2[13] = fmaf(hk, w3v.y, h2[13]);
            h2[14] = fmaf(hk, w3v.z, h2[14]);
            h2[15] = fmaf(hk, w3v.w, h2[15]);
        }
        float o = bn[0];
#pragma unroll
        for (int kk = 0; kk < HID; ++kk)
            o = fmaf(fmaxf(h2[kk], 0.f), Wn[kk], o);

        const int myb = nc / N;
        const float val = valid ? o : 0.f;

        // per-batch masked block reduction (deterministic)
        for (int b = 0; b < B; ++b) {
            float s = (myb == b) ? val : 0.f;
#pragma unroll
            for (int off = 32; off; off >>= 1) s += __shfl_down(s, off, 64);
            if ((t & 63) == 0) sred[wave * B + b] = s;
        }
        __syncthreads();
        if (t == 0) {
            for (int b = 0; b < B; ++b)
                pN[(long)b * nodeBlocks + bx] =
                    (sred[0 * B + b] + sred[1 * B + b]) +
                    (sred[2 * B + b] + sred[3 * B + b]);
        }
    } else {
        // ---------------- col path (R8 structure, tiny) ----------------
        const int cb = bx - nodeBlocks;
        const int totC = B * C;
        const int c = cb * NTHR + t;
        const bool valid = (c < totC);
        const int cc = valid ? c : totC - 1;
        const float4* __restrict__ row = (const float4*)(xc + (long)cc * CF_IN);

        float acc[HID];
        {
            const float4* __restrict__ bb = (const float4*)bc1;  // uniform
            const float4 c0 = bb[0], c1 = bb[1], c2 = bb[2], c3 = bb[3];
            acc[0]=c0.x;  acc[1]=c0.y;  acc[2]=c0.z;  acc[3]=c0.w;
            acc[4]=c1.x;  acc[5]=c1.y;  acc[6]=c1.z;  acc[7]=c1.w;
            acc[8]=c2.x;  acc[9]=c2.y;  acc[10]=c2.z; acc[11]=c2.w;
            acc[12]=c3.x; acc[13]=c3.y; acc[14]=c3.z; acc[15]=c3.w;
        }
#pragma unroll 4
        for (int k4 = 0; k4 < CF_IN / 4; ++k4) {
            const float4 xv = row[k4];
            const float4* __restrict__ wb =
                (const float4*)(Wc1 + k4 * 4 * HID);
#pragma unroll
            for (int r = 0; r < 4; ++r) {
                const float xs = (r == 0) ? xv.x : (r == 1) ? xv.y
                               : (r == 2) ? xv.z : xv.w;
                const float4 w0  = wb[r * 4 + 0];
                const float4 w1v = wb[r * 4 + 1];
                const float4 w2v = wb[r * 4 + 2];
                const float4 w3v = wb[r * 4 + 3];
                acc[0]  = fmaf(xs, w0.x,  acc[0]);
                acc[1]  = fmaf(xs, w0.y,  acc[1]);
                acc[2]  = fmaf(xs, w0.z,  acc[2]);
                acc[3]  = fmaf(xs, w0.w,  acc[3]);
                acc[4]  = fmaf(xs, w1v.x, acc[4]);
                acc[5]  = fmaf(xs, w1v.y, acc[5]);
                acc[6]  = fmaf(xs, w1v.z, acc[6]);
                acc[7]  = fmaf(xs, w1v.w, acc[7]);
                acc[8]  = fmaf(xs, w2v.x, acc[8]);
                acc[9]  = fmaf(xs, w2v.y, acc[9]);
                acc[10] = fmaf(xs, w2v.z, acc[10]);
                acc[11] = fmaf(xs, w2v.w, acc[11]);
                acc[12] = fmaf(xs, w3v.x, acc[12]);
                acc[13] = fmaf(xs, w3v.y, acc[13]);
                acc[14] = fmaf(xs, w3v.z, acc[14]);
                acc[15] = fmaf(xs, w3v.w, acc[15]);
            }
        }
        float o = bc2[0];
#pragma unroll
        for (int j = 0; j < HID; ++j)
            o = fmaf(fmaxf(acc[j], 0.f), Wc2[j], o);

        const int myb = cc / C;
        const float val = valid ? o : 0.f;
        for (int b = 0; b < B; ++b) {
            float s = (myb == b) ? val : 0.f;
#pragma unroll
            for (int off = 32; off; off >>= 1) s += __shfl_down(s, off, 64);
            if ((t & 63) == 0) sred[wave * B + b] = s;
        }
        __syncthreads();
        if (t == 0) {
            for (int b = 0; b < B; ++b)
                pC[(long)b * colBlocks + cb] =
                    (sred[0 * B + b] + sred[1 * B + b]) +
                    (sred[2 * B + b] + sred[3 * B + b]);
        }
    }
}

__global__ __launch_bounds__(256) void finish_kernel(
    const float* __restrict__ pN, const float* __restrict__ pC,
    const float* __restrict__ Wf, const float* __restrict__ bf,
    const float* __restrict__ Wo, const float* __restrict__ bo,
    float* __restrict__ out, int nWN, int nWC, int N, int C, int B)
{
    const int t = threadIdx.x;
    const int wave = t >> 6, lane = t & 63;
    __shared__ float s[16];

    for (int p = wave; p < 2 * B; p += 4) {
        const int b = p >> 1, kind = p & 1;
        float v = 0.f;
        if (kind == 0) {
            for (int i = lane; i < nWN; i += 64) v += pN[(long)b * nWN + i];
        } else {
            for (int i = lane; i < nWC; i += 64) v += pC[(long)b * nWC + i];
        }
#pragma unroll
        for (int off = 32; off; off >>= 1) v += __shfl_down(v, off, 64);
        if (lane == 0) s[p] = v;
    }
    __syncthreads();

    if (t == 0) {
        for (int b = 0; b < B; ++b) {
            const float navg = s[2 * b + 0] / (float)N;
            const float cavg = s[2 * b + 1] / (float)C;
            float o = bo[0];
#pragma unroll
            for (int j = 0; j < HID; ++j) {
                const float h = fmaf(navg, Wf[j], fmaf(cavg, Wf[HID + j], bf[j]));
                o = fmaf(fmaxf(h, 0.f), Wo[j], o);
            }
            out[b] = o;
        }
    }
}

extern "C" void kernel_launch(void* const* d_in, const int* in_sizes, int n_in,
                              void* d_out, int out_size, void* d_ws, size_t ws_size,
                              hipStream_t stream) {
    const float* x   = (const float*)d_in[0];
    const float* xc  = (const float*)d_in[1];
    // d_in[2] = edge_index: unused (row==col degeneracy -> GCN aggregation is identity)
    const float* W1  = (const float*)d_in[3];
    const float* b1  = (const float*)d_in[4];
    const float* W2  = (const float*)d_in[5];
    const float* b2  = (const float*)d_in[6];
    const float* Wn  = (const float*)d_in[7];
    const float* bn  = (const float*)d_in[8];
    const float* Wc1 = (const float*)d_in[9];
    const float* bc1 = (const float*)d_in[10];
    const float* Wc2 = (const float*)d_in[11];
    const float* bc2 = (const float*)d_in[12];
    const float* Wf  = (const float*)d_in[13];
    const float* bf  = (const float*)d_in[14];
    const float* Wo  = (const float*)d_in[15];
    const float* bo  = (const float*)d_in[16];

    const int C = 1000;
    const int B = in_sizes[1] / (C * CF_IN);     // col_features [B, 1000, 64]
    const int N = in_sizes[0] / (B * F_IN);      // node_features [B, N, 128]
    const int totalN = B * N;                    // 200000

    const int nodeBlocks = (totalN + NTHR - 1) / NTHR;   // 782
    const int colBlocks  = (B * C + NTHR - 1) / NTHR;    // 8

    float* pN = (float*)d_ws;                    // [B][nodeBlocks], always overwritten
    float* pC = pN + (long)B * nodeBlocks;       // [B][colBlocks]

    fused_kernel<<<nodeBlocks + colBlocks, NTHR, 0, stream>>>(
        x, xc, W1, b1, W2, b2, Wn, bn, Wc1, bc1, Wc2, bc2,
        pN, pC, N, B, C, totalN, nodeBlocks, colBlocks);
    finish_kernel<<<1, 256, 0, stream>>>(pN, pC, Wf, bf, Wo, bo, (float*)d_out,
                                         nodeBlocks, colBlocks, N, C, B);
}

// Round 12
// 34.246 us; speedup vs baseline: 2.9869x; 1.3239x over previous
//
#include <hip/hip_runtime.h>

#define F_IN  128
#define HID   16
#define CF_IN 64
#define NTHR  256

typedef __attribute__((ext_vector_type(8))) short bf16x8;
typedef __attribute__((ext_vector_type(4))) float f32x4;

__device__ __forceinline__ unsigned short bf16rne(float f) {
    unsigned u = __float_as_uint(f);
    u += 0x7fffu + ((u >> 16) & 1u);
    return (unsigned short)(u >> 16);
}
__device__ __forceinline__ float bf16tof(unsigned short h) {
    return __uint_as_float(((unsigned)h) << 16);
}

// GCN aggregation is exactly the identity here (row==col after the reference's
// broadcast+reshape), so each conv is x@W + b. edge_index is never read.
//
// Node path (per 64-node wave, autonomous, no hot-loop barriers):
//   - layer 1 via mfma_f32_16x16x32_bf16: W1 split hi+lo bf16 (2 MFMAs into the
//     same f32 acc -> W rounding ~2^-16 rel; x single bf16, per-node-iid error
//     averages out over 100K nodes). B-frags live in 32 VGPRs for the whole
//     K-loop -> the per-lane weight-delivery wall (R1/R5/R8's ~21us) is gone.
//   - x staged coalesced (16 full 64B lines/instr), RNE-packed to bf16, XOR-
//     swizzled ds_write (write-side and read-side use the same involution).
//   - layers 2/3 scalar fp32 after a stride-17 LDS transpose (conflict-free).
// A/B frag k-ordering is self-consistent (same assumption on both operands ->
// any k-permutation cancels in the dot product); C layout is the verified
// col=lane&15, row=(lane>>4)*4+r.

__global__ __launch_bounds__(NTHR) void fused_kernel(
    const float* __restrict__ x, const float* __restrict__ xc,
    const float* __restrict__ W1, const float* __restrict__ b1,
    const float* __restrict__ W2, const float* __restrict__ b2,
    const float* __restrict__ Wn, const float* __restrict__ bn,
    const float* __restrict__ Wc1, const float* __restrict__ bc1,
    const float* __restrict__ Wc2, const float* __restrict__ bc2,
    float* __restrict__ pN, float* __restrict__ pC,
    int N, int B, int C, int totalN, int nodeBlocks, int colBlocks)
{
    __shared__ __align__(16) unsigned char smem[33792]; // 16KB xstage + 4x4352B h1T
    __shared__ float sred[4 * 8];
    const int t = threadIdx.x;
    const int bx = blockIdx.x;
    const int wave = t >> 6, lane = t & 63;

    if (bx < nodeBlocks) {
        // ---------------- node path ----------------
        unsigned char* __restrict__ xs = smem + wave * 4096;
        float* __restrict__ h1w = (float*)(smem + 16384 + wave * 4352);
        const long tileBase = (long)bx * 256 + (long)wave * 64;
        const long maxNode = (long)totalN - 1;
        const float4* __restrict__ gx = (const float4*)x;
        const int n15 = lane & 15, q = lane >> 4;

        // coalesced x loads for one K=32 chunk: instr i covers 8 nodes x 128B
#define XLOAD(KC)                                                        \
        _Pragma("unroll")                                                \
        for (int i = 0; i < 8; ++i) {                                    \
            long m = tileBase + i * 8 + (lane >> 3);                     \
            if (m > maxNode) m = maxNode;                                \
            v[i] = gx[m * 32 + (KC) * 8 + (lane & 7)];                   \
        }

        float4 v[8];
        XLOAD(0)

        // B fragments: W1 hi/lo bf16 split, built once, held in VGPRs
        bf16x8 bhi[4], blo[4];
#pragma unroll
        for (int kc = 0; kc < 4; ++kc) {
#pragma unroll
            for (int r = 0; r < 4; ++r) {
                const int k0 = kc * 32 + q * 8 + 2 * r;
                const float w0 = W1[k0 * HID + n15];
                const float w1 = W1[(k0 + 1) * HID + n15];
                const unsigned short h0 = bf16rne(w0), h1b = bf16rne(w1);
                bhi[kc][2 * r]     = (short)h0;
                bhi[kc][2 * r + 1] = (short)h1b;
                blo[kc][2 * r]     = (short)bf16rne(w0 - bf16tof(h0));
                blo[kc][2 * r + 1] = (short)bf16rne(w1 - bf16tof(h1b));
            }
        }

        const float bj = b1[n15];
        f32x4 acc[4];
#pragma unroll
        for (int s = 0; s < 4; ++s) acc[s] = (f32x4){bj, bj, bj, bj};

#pragma unroll
        for (int kc = 0; kc < 4; ++kc) {
            // pack to bf16 + swizzled ds_write (q' = q ^ (node&3), both sides)
#pragma unroll
            for (int i = 0; i < 8; ++i) {
                const unsigned u01 = (unsigned)bf16rne(v[i].x)
                                   | ((unsigned)bf16rne(v[i].y) << 16);
                const unsigned u23 = (unsigned)bf16rne(v[i].z)
                                   | ((unsigned)bf16rne(v[i].w) << 16);
                const int m  = i * 8 + (lane >> 3);
                const int qq = (lane >> 1) & 3, h = lane & 1;
                *(uint2*)(xs + m * 64 + ((qq ^ (m & 3)) << 4) + h * 8) =
                    make_uint2(u01, u23);
            }
            if (kc < 3) { XLOAD(kc + 1) }   // prefetch flies over reads+MFMA
            asm volatile("" ::: "memory");  // pin ds_read after ds_write
#pragma unroll
            for (int s = 0; s < 4; ++s) {
                const int m = s * 16 + n15;
                const bf16x8 a =
                    *(const bf16x8*)(xs + m * 64 + ((q ^ (lane & 3)) << 4));
                acc[s] = __builtin_amdgcn_mfma_f32_16x16x32_bf16(
                             a, bhi[kc], acc[s], 0, 0, 0);
                acc[s] = __builtin_amdgcn_mfma_f32_16x16x32_bf16(
                             a, blo[kc], acc[s], 0, 0, 0);
            }
        }
#undef XLOAD

        // C-frag (row=(lane>>4)*4+r, col=lane&15) -> relu -> LDS transpose
#pragma unroll
        for (int s = 0; s < 4; ++s)
#pragma unroll
            for (int r = 0; r < 4; ++r) {
                const int nl = s * 16 + q * 4 + r;
                h1w[nl * 17 + n15] = fmaxf(acc[s][r], 0.f);
            }
        asm volatile("" ::: "memory");
        float h1[HID];
#pragma unroll
        for (int k = 0; k < HID; ++k) h1[k] = h1w[lane * 17 + k];  // 17: bijective banks

        // layers 2/3: scalar fp32, uniform weight derefs (small, R8-proven)
        float h2[HID];
        {
            const float4* __restrict__ bb = (const float4*)b2;
            const float4 c0 = bb[0], c1 = bb[1], c2 = bb[2], c3 = bb[3];
            h2[0]=c0.x;  h2[1]=c0.y;  h2[2]=c0.z;  h2[3]=c0.w;
            h2[4]=c1.x;  h2[5]=c1.y;  h2[6]=c1.z;  h2[7]=c1.w;
            h2[8]=c2.x;  h2[9]=c2.y;  h2[10]=c2.z; h2[11]=c2.w;
            h2[12]=c3.x; h2[13]=c3.y; h2[14]=c3.z; h2[15]=c3.w;
        }
#pragma unroll
        for (int kk = 0; kk < HID; ++kk) {
            const float hk = h1[kk];
            const float4* __restrict__ wr = (const float4*)(W2 + kk * HID);
            const float4 w0 = wr[0], w1v = wr[1], w2v = wr[2], w3v = wr[3];
            h2[0]  = fmaf(hk, w0.x,  h2[0]);  h2[1]  = fmaf(hk, w0.y,  h2[1]);
            h2[2]  = fmaf(hk, w0.z,  h2[2]);  h2[3]  = fmaf(hk, w0.w,  h2[3]);
            h2[4]  = fmaf(hk, w1v.x, h2[4]);  h2[5]  = fmaf(hk, w1v.y, h2[5]);
            h2[6]  = fmaf(hk, w1v.z, h2[6]);  h2[7]  = fmaf(hk, w1v.w, h2[7]);
            h2[8]  = fmaf(hk, w2v.x, h2[8]);  h2[9]  = fmaf(hk, w2v.y, h2[9]);
            h2[10] = fmaf(hk, w2v.z, h2[10]); h2[11] = fmaf(hk, w2v.w, h2[11]);
            h2[12] = fmaf(hk, w3v.x, h2[12]); h2[13] = fmaf(hk, w3v.y, h2[13]);
            h2[14] = fmaf(hk, w3v.z, h2[14]); h2[15] = fmaf(hk, w3v.w, h2[15]);
        }
        float o = bn[0];
#pragma unroll
        for (int kk = 0; kk < HID; ++kk)
            o = fmaf(fmaxf(h2[kk], 0.f), Wn[kk], o);

        const long node = tileBase + lane;
        const bool valid = (node < totalN);
        const long nc = valid ? node : maxNode;
        const int myb = (int)(nc / N);
        const float val = valid ? o : 0.f;

        for (int b = 0; b < B; ++b) {
            float s = (myb == b) ? val : 0.f;
#pragma unroll
            for (int off = 32; off; off >>= 1) s += __shfl_down(s, off, 64);
            if (lane == 0) sred[wave * B + b] = s;
        }
        __syncthreads();
        if (t == 0) {
            for (int b = 0; b < B; ++b)
                pN[(long)b * nodeBlocks + bx] =
                    (sred[0 * B + b] + sred[1 * B + b]) +
                    (sred[2 * B + b] + sred[3 * B + b]);
        }
    } else {
        // ---------------- col path (R8-proven, tiny) ----------------
        const int cb = bx - nodeBlocks;
        const int totC = B * C;
        const int c = cb * NTHR + t;
        const bool valid = (c < totC);
        const int cc = valid ? c : totC - 1;
        const float4* __restrict__ row = (const float4*)(xc + (long)cc * CF_IN);

        float acc[HID];
        {
            const float4* __restrict__ bb = (const float4*)bc1;
            const float4 c0 = bb[0], c1 = bb[1], c2 = bb[2], c3 = bb[3];
            acc[0]=c0.x;  acc[1]=c0.y;  acc[2]=c0.z;  acc[3]=c0.w;
            acc[4]=c1.x;  acc[5]=c1.y;  acc[6]=c1.z;  acc[7]=c1.w;
            acc[8]=c2.x;  acc[9]=c2.y;  acc[10]=c2.z; acc[11]=c2.w;
            acc[12]=c3.x; acc[13]=c3.y; acc[14]=c3.z; acc[15]=c3.w;
        }
#pragma unroll 4
        for (int k4 = 0; k4 < CF_IN / 4; ++k4) {
            const float4 xv = row[k4];
            const float4* __restrict__ wb = (const float4*)(Wc1 + k4 * 4 * HID);
#pragma unroll
            for (int r = 0; r < 4; ++r) {
                const float xs = (r == 0) ? xv.x : (r == 1) ? xv.y
                               : (r == 2) ? xv.z : xv.w;
                const float4 w0  = wb[r * 4 + 0];
                const float4 w1v = wb[r * 4 + 1];
                const float4 w2v = wb[r * 4 + 2];
                const float4 w3v = wb[r * 4 + 3];
                acc[0]  = fmaf(xs, w0.x,  acc[0]);  acc[1]  = fmaf(xs, w0.y,  acc[1]);
                acc[2]  = fmaf(xs, w0.z,  acc[2]);  acc[3]  = fmaf(xs, w0.w,  acc[3]);
                acc[4]  = fmaf(xs, w1v.x, acc[4]);  acc[5]  = fmaf(xs, w1v.y, acc[5]);
                acc[6]  = fmaf(xs, w1v.z, acc[6]);  acc[7]  = fmaf(xs, w1v.w, acc[7]);
                acc[8]  = fmaf(xs, w2v.x, acc[8]);  acc[9]  = fmaf(xs, w2v.y, acc[9]);
                acc[10] = fmaf(xs, w2v.z, acc[10]); acc[11] = fmaf(xs, w2v.w, acc[11]);
                acc[12] = fmaf(xs, w3v.x, acc[12]); acc[13] = fmaf(xs, w3v.y, acc[13]);
                acc[14] = fmaf(xs, w3v.z, acc[14]); acc[15] = fmaf(xs, w3v.w, acc[15]);
            }
        }
        float o = bc2[0];
#pragma unroll
        for (int j = 0; j < HID; ++j)
            o = fmaf(fmaxf(acc[j], 0.f), Wc2[j], o);

        const int myb = cc / C;
        const float val = valid ? o : 0.f;
        for (int b = 0; b < B; ++b) {
            float s = (myb == b) ? val : 0.f;
#pragma unroll
            for (int off = 32; off; off >>= 1) s += __shfl_down(s, off, 64);
            if (lane == 0) sred[wave * B + b] = s;
        }
        __syncthreads();
        if (t == 0) {
            for (int b = 0; b < B; ++b)
                pC[(long)b * colBlocks + cb] =
                    (sred[0 * B + b] + sred[1 * B + b]) +
                    (sred[2 * B + b] + sred[3 * B + b]);
        }
    }
}

__global__ __launch_bounds__(256) void finish_kernel(
    const float* __restrict__ pN, const float* __restrict__ pC,
    const float* __restrict__ Wf, const float* __restrict__ bf,
    const float* __restrict__ Wo, const float* __restrict__ bo,
    float* __restrict__ out, int nWN, int nWC, int N, int C, int B)
{
    const int t = threadIdx.x;
    const int wave = t >> 6, lane = t & 63;
    __shared__ float s[16];

    for (int p = wave; p < 2 * B; p += 4) {
        const int b = p >> 1, kind = p & 1;
        float v = 0.f;
        if (kind == 0) {
            for (int i = lane; i < nWN; i += 64) v += pN[(long)b * nWN + i];
        } else {
            for (int i = lane; i < nWC; i += 64) v += pC[(long)b * nWC + i];
        }
#pragma unroll
        for (int off = 32; off; off >>= 1) v += __shfl_down(v, off, 64);
        if (lane == 0) s[p] = v;
    }
    __syncthreads();

    if (t == 0) {
        for (int b = 0; b < B; ++b) {
            const float navg = s[2 * b + 0] / (float)N;
            const float cavg = s[2 * b + 1] / (float)C;
            float o = bo[0];
#pragma unroll
            for (int j = 0; j < HID; ++j) {
                const float h = fmaf(navg, Wf[j], fmaf(cavg, Wf[HID + j], bf[j]));
                o = fmaf(fmaxf(h, 0.f), Wo[j], o);
            }
            out[b] = o;
        }
    }
}

extern "C" void kernel_launch(void* const* d_in, const int* in_sizes, int n_in,
                              void* d_out, int out_size, void* d_ws, size_t ws_size,
                              hipStream_t stream) {
    const float* x   = (const float*)d_in[0];
    const float* xc  = (const float*)d_in[1];
    // d_in[2] = edge_index: unused (row==col degeneracy -> GCN aggregation is identity)
    const float* W1  = (const float*)d_in[3];
    const float* b1  = (const float*)d_in[4];
    const float* W2  = (const float*)d_in[5];
    const float* b2  = (const float*)d_in[6];
    const float* Wn  = (const float*)d_in[7];
    const float* bn  = (const float*)d_in[8];
    const float* Wc1 = (const float*)d_in[9];
    const float* bc1 = (const float*)d_in[10];
    const float* Wc2 = (const float*)d_in[11];
    const float* bc2 = (const float*)d_in[12];
    const float* Wf  = (const float*)d_in[13];
    const float* bf  = (const float*)d_in[14];
    const float* Wo  = (const float*)d_in[15];
    const float* bo  = (const float*)d_in[16];

    const int C = 1000;
    const int B = in_sizes[1] / (C * CF_IN);     // col_features [B, 1000, 64]
    const int N = in_sizes[0] / (B * F_IN);      // node_features [B, N, 128]
    const int totalN = B * N;                    // 200000

    const int nodeBlocks = (totalN + NTHR - 1) / NTHR;   // 782
    const int colBlocks  = (B * C + NTHR - 1) / NTHR;    // 8

    float* pN = (float*)d_ws;                    // [B][nodeBlocks], always overwritten
    float* pC = pN + (long)B * nodeBlocks;       // [B][colBlocks]

    fused_kernel<<<nodeBlocks + colBlocks, NTHR, 0, stream>>>(
        x, xc, W1, b1, W2, b2, Wn, bn, Wc1, bc1, Wc2, bc2,
        pN, pC, N, B, C, totalN, nodeBlocks, colBlocks);
    finish_kernel<<<1, 256, 0, stream>>>(pN, pC, Wf, bf, Wo, bo, (float*)d_out,
                                         nodeBlocks, colBlocks, N, C, B);
}